// Round 1
// baseline (15126.100 us; speedup 1.0000x reference)
//
#include <hip/hip_runtime.h>
#include <hip/hip_bf16.h>
#include <stdint.h>

// GroupLinear: out[l,o] = sum_{g,i,j} x1[l,g*64+i]*x2[l,g*64+j]*W[o,(g*64+i)*64+j] + b[o]
// Round 8: software-pipelined staging. At iter t: writeB(tile t+1) from regs loaded
// at t-1 (vmcnt dependency ~1 iter old -> free), issue loadB(t+2) fresh. Raw
// s_barrier + asm lgkmcnt(0) (no vmcnt drain) keeps prefetch loads in flight
// across the barrier — removes the per-iter vmcnt(0) stall that held MfmaUtil at 26%.
// w_convert: grid-strided, nontemporal fp32 reads, 16B bf16 stores (Wb stays in L3).
// Facts: global_load_lds not L2-retained (r2/r3); reg live set ~160/thread blocks 4 wg/CU.

#define L_DIM 2048
#define H_DIM 1024
#define O_DIM 1024
#define KDIM  65536

constexpr int BM = 128, BN = 128;
constexpr int SPLITK = 4;
constexpr int KITERS = 1024 / SPLITK;   // 256 (g,i) pairs per block, K-advance 64 each
constexpr int BSTR = 72;                // B LDS row stride in shorts (64+8 pad)

typedef __attribute__((ext_vector_type(8))) short bf16x8;
typedef __attribute__((ext_vector_type(8))) unsigned short u16x8;
typedef __attribute__((ext_vector_type(4))) float f32x4;
typedef __attribute__((ext_vector_type(4))) unsigned int u32x4;

__device__ __forceinline__ unsigned short f2b(float x) {
    __hip_bfloat16 h = __float2bfloat16(x);
    unsigned short u;
    __builtin_memcpy(&u, &h, 2);
    return u;
}

__device__ __forceinline__ unsigned pk2(float a, float b) {
    float2 t; t.x = a; t.y = b;
    __hip_bfloat162 h = __float22bfloat162_rn(t);   // v_cvt_pk_bf16_f32
    unsigned u;
    __builtin_memcpy(&u, &h, 4);
    return u;
}

// ---- W fp32 -> bf16: grid-strided, nontemporal fp32 reads, 16B stores ----
__global__ __launch_bounds__(256) void w_convert(const float* __restrict__ W,
                                                 unsigned short* __restrict__ Wb) {
    const size_t nchunk = (size_t)O_DIM * KDIM / 16;          // 16 floats per chunk
    const size_t stride = (size_t)gridDim.x * 256;
    const f32x4* src = reinterpret_cast<const f32x4*>(W);
    u16x8* dst = reinterpret_cast<u16x8*>(Wb);
    for (size_t c = (size_t)blockIdx.x * 256 + threadIdx.x; c < nchunk; c += stride) {
        f32x4 a0 = __builtin_nontemporal_load(src + c * 4 + 0);
        f32x4 a1 = __builtin_nontemporal_load(src + c * 4 + 1);
        f32x4 a2 = __builtin_nontemporal_load(src + c * 4 + 2);
        f32x4 a3 = __builtin_nontemporal_load(src + c * 4 + 3);
        u32x4 p0, p1;
        p0[0] = pk2(a0.x, a0.y); p0[1] = pk2(a0.z, a0.w);
        p0[2] = pk2(a1.x, a1.y); p0[3] = pk2(a1.z, a1.w);
        p1[0] = pk2(a2.x, a2.y); p1[1] = pk2(a2.z, a2.w);
        p1[2] = pk2(a3.x, a3.y); p1[3] = pk2(a3.z, a3.w);
        dst[c * 2 + 0] = __builtin_bit_cast(u16x8, p0);
        dst[c * 2 + 1] = __builtin_bit_cast(u16x8, p1);
    }
}

// ---- out[l][o] = bias[o] (atomic-accumulation base) ----
__global__ __launch_bounds__(256) void gl_init(const float* __restrict__ bias,
                                               float* __restrict__ out) {
    int idx = blockIdx.x * 256 + threadIdx.x;
    int o = (idx * 4) & (O_DIM - 1);
    f32x4 bv = *reinterpret_cast<const f32x4*>(bias + o);
    reinterpret_cast<f32x4*>(out)[idx] = bv;
}

// ---- main GEMM ----
__global__ __launch_bounds__(256, 2) void gl_gemm(const float* __restrict__ x1,
                                                  const float* __restrict__ x2,
                                                  const unsigned short* __restrict__ Wb,
                                                  float* __restrict__ out) {
    __shared__ unsigned short Bb[2][BN * BSTR];   // 2 x 18 KB

    const int tid  = threadIdx.x;
    const int lane = tid & 63;
    const int wid  = tid >> 6;
    const int wm   = (wid >> 1) * 64;
    const int wn   = (wid & 1) * 64;
    const int quad = lane >> 4;
    const int l16  = lane & 15;

    // n in low 3 bits -> all blocks sharing one W n-slab co-locate per XCD (L2 reuse)
    const int id  = blockIdx.x;
    const int n0  = (id & 7) * BN;
    const int m0  = ((id >> 3) & 15) * BM;
    const int kk0 = (id >> 7) * KITERS;     // (g,i)-pair index base, multiple of 64

    unsigned aoff[4];                       // x1/x2 row offsets (floats)
    #pragma unroll
    for (int t = 0; t < 4; ++t)
        aoff[t] = (unsigned)(m0 + wm + t * 16 + l16) * H_DIM;
    const unsigned qo = quad * 8;

    // B staging: thread covers rows (tid>>3)+32p, 16B chunk (tid&7)*8 shorts
    const int brow = tid >> 3;
    const int bcol = (tid & 7) * 8;
    const unsigned short* gB = Wb + (size_t)(n0 + brow) * KDIM + (size_t)kk0 * 64 + bcol;
    const int bl = brow * BSTR + bcol;

    f32x4 acc[4][4] = {};
    f32x4 x2c[4][4];        // per-g x2 slice cache: [mt][ks*2+half]
    u16x8 rB[2][4];         // 2 staging reg sets: set k&1 holds tile k (in flight ~2 iters)
    float xc[4], xn[4];     // x1 current / next

    auto loadB = [&](int it) {              // tile it -> set it&1
        const unsigned short* gp = gB + (size_t)it * 64;
        u16x8* r = rB[it & 1];
        #pragma unroll
        for (int p = 0; p < 4; ++p)
            r[p] = *reinterpret_cast<const u16x8*>(gp + (size_t)p * 32 * KDIM);
    };
    auto writeB = [&](int buf, int set) {
        const u16x8* r = rB[set];
        #pragma unroll
        for (int p = 0; p < 4; ++p)
            *reinterpret_cast<u16x8*>(&Bb[buf][bl + p * 32 * BSTR]) = r[p];
    };
    auto loadX1 = [&](int it, float (&v)[4]) {
        const unsigned kc = (unsigned)(kk0 + it);   // x1 col = g*64+i
        #pragma unroll
        for (int mt = 0; mt < 4; ++mt)
            v[mt] = x1[aoff[mt] + kc];
    };

    // prologue: stage tile 0 (the one vmcnt-latency stall we pay), prefetch tile 1 regs
    loadB(0);
    loadX1(0, xc);
    writeB(0, 0);                           // compiler waits (counted) on tile-0 loads
    loadB(1);
    __builtin_amdgcn_sched_barrier(0);
    asm volatile("s_waitcnt lgkmcnt(0)" ::: "memory");
    __builtin_amdgcn_s_barrier();
    __builtin_amdgcn_sched_barrier(0);

    for (int it = 0; it < KITERS; ++it) {
        const int cur = it & 1;

        if ((it & 63) == 0) {               // refill x2c for this g (wave-uniform branch)
            const unsigned gb = (unsigned)(kk0 + it);   // col base = g*64
            #pragma unroll
            for (int mt = 0; mt < 4; ++mt) {
                const float* p = x2 + aoff[mt] + gb + qo;
                x2c[mt][0] = *reinterpret_cast<const f32x4*>(p);
                x2c[mt][1] = *reinterpret_cast<const f32x4*>(p + 4);
                x2c[mt][2] = *reinterpret_cast<const f32x4*>(p + 32);
                x2c[mt][3] = *reinterpret_cast<const f32x4*>(p + 36);
            }
        }

        const bool hn1 = (it + 1 < KITERS);
        const bool hn2 = (it + 2 < KITERS);
        // stage tile it+1 into LDS from regs loaded at iter it-1 (vmcnt dep is old -> free)
        if (hn1) writeB(cur ^ 1, (it + 1) & 1);
        // issue prefetches: tile it+2 regs (in flight across the barrier), x1 for it+1
        if (hn2) loadB(it + 2);
        if (hn1) loadX1(it + 1, xn);

        // compute from Bb[cur] with register-built A-frags
        #pragma unroll
        for (int ks = 0; ks < 2; ++ks) {
            const int koff = ks * 32 + qo;
            bf16x8 af[4], bfr[4];
            #pragma unroll
            for (int nt = 0; nt < 4; ++nt)
                bfr[nt] = *reinterpret_cast<const bf16x8*>(
                    &Bb[cur][(wn + nt * 16 + l16) * BSTR + koff]);
            #pragma unroll
            for (int mt = 0; mt < 4; ++mt) {
                f32x4 lo = x2c[mt][ks * 2]     * xc[mt];
                f32x4 hi = x2c[mt][ks * 2 + 1] * xc[mt];
                u32x4 pk;
                pk[0] = pk2(lo.x, lo.y); pk[1] = pk2(lo.z, lo.w);
                pk[2] = pk2(hi.x, hi.y); pk[3] = pk2(hi.z, hi.w);
                af[mt] = __builtin_bit_cast(bf16x8, pk);
            }
            #pragma unroll
            for (int mt = 0; mt < 4; ++mt)
                #pragma unroll
                for (int nt = 0; nt < 4; ++nt)
                    acc[mt][nt] = __builtin_amdgcn_mfma_f32_16x16x32_bf16(
                        af[mt], bfr[nt], acc[mt][nt], 0, 0, 0);
        }

        #pragma unroll
        for (int mt = 0; mt < 4; ++mt) xc[mt] = xn[mt];

        // raw barrier: drain LDS ops only; tile-(it+2) global loads stay in flight
        __builtin_amdgcn_sched_barrier(0);
        asm volatile("s_waitcnt lgkmcnt(0)" ::: "memory");
        __builtin_amdgcn_s_barrier();
        __builtin_amdgcn_sched_barrier(0);
    }

    // Epilogue: split-K partials. C/D: row(m)=quad*4+reg, col(n)=lane&15.
    #pragma unroll
    for (int mt = 0; mt < 4; ++mt) {
        const int mb = m0 + wm + mt * 16 + quad * 4;
        #pragma unroll
        for (int nt = 0; nt < 4; ++nt) {
            const int n = n0 + wn + nt * 16 + l16;
            #pragma unroll
            for (int r = 0; r < 4; ++r)
                unsafeAtomicAdd(&out[(mb + r) * O_DIM + n], acc[mt][nt][r]);
        }
    }
}

// ---- fallback (fp32 W, LDS staging) if workspace too small for bf16 W ----
constexpr int STR = 72;
__global__ __launch_bounds__(256, 2) void gl_gemm_fb(const float* __restrict__ x1,
                                                     const float* __restrict__ x2,
                                                     const float* __restrict__ W,
                                                     float* __restrict__ out) {
    __shared__ unsigned short Ab[BM * STR];
    __shared__ unsigned short Bb2[BM * STR];

    const int tid  = threadIdx.x;
    const int lane = tid & 63;
    const int wid  = tid >> 6;
    const int wm   = (wid >> 1) * 64;
    const int wn   = (wid & 1) * 64;
    const int quad = lane >> 4;
    const int l16  = lane & 15;
    const int m0   = blockIdx.y * BM;
    const int n0   = blockIdx.x * BN;
    const int kk0  = blockIdx.z * (1024 / 4);

    const int srow = tid >> 4;
    const int scol = (tid & 15) * 4;

    f32x4 acc[4][4] = {};

    for (int kk = kk0; kk < kk0 + (1024 / 4); ++kk) {
        const int g = kk >> 6;
        const int i = kk & 63;
        __syncthreads();
        #pragma unroll
        for (int c = 0; c < 8; ++c) {
            const int r = srow + c * 16;
            const float x1v = x1[(m0 + r) * H_DIM + g * 64 + i];
            const f32x4 v = *reinterpret_cast<const f32x4*>(
                &x2[(m0 + r) * H_DIM + g * 64 + scol]);
            ushort4 h;
            h.x = f2b(v.x * x1v); h.y = f2b(v.y * x1v);
            h.z = f2b(v.z * x1v); h.w = f2b(v.w * x1v);
            *reinterpret_cast<ushort4*>(&Ab[r * STR + scol]) = h;
        }
        #pragma unroll
        for (int c = 0; c < 8; ++c) {
            const int r = srow + c * 16;
            const f32x4 v = *reinterpret_cast<const f32x4*>(
                &W[(size_t)(n0 + r) * KDIM + (size_t)kk * 64 + scol]);
            ushort4 h;
            h.x = f2b(v.x); h.y = f2b(v.y); h.z = f2b(v.z); h.w = f2b(v.w);
            *reinterpret_cast<ushort4*>(&Bb2[r * STR + scol]) = h;
        }
        __syncthreads();
        #pragma unroll
        for (int ks = 0; ks < 2; ++ks) {
            const int koff = ks * 32 + quad * 8;
            bf16x8 af[4], bfr[4];
            #pragma unroll
            for (int mt = 0; mt < 4; ++mt)
                af[mt] = *reinterpret_cast<const bf16x8*>(
                    &Ab[(wm + mt * 16 + l16) * STR + koff]);
            #pragma unroll
            for (int nt = 0; nt < 4; ++nt)
                bfr[nt] = *reinterpret_cast<const bf16x8*>(
                    &Bb2[(wn + nt * 16 + l16) * STR + koff]);
            #pragma unroll
            for (int mt = 0; mt < 4; ++mt)
                #pragma unroll
                for (int nt = 0; nt < 4; ++nt)
                    acc[mt][nt] = __builtin_amdgcn_mfma_f32_16x16x32_bf16(
                        af[mt], bfr[nt], acc[mt][nt], 0, 0, 0);
        }
    }
    #pragma unroll
    for (int mt = 0; mt < 4; ++mt) {
        const int mb = m0 + wm + mt * 16 + quad * 4;
        #pragma unroll
        for (int nt = 0; nt < 4; ++nt) {
            const int n = n0 + wn + nt * 16 + l16;
            #pragma unroll
            for (int r = 0; r < 4; ++r)
                unsafeAtomicAdd(&out[(mb + r) * O_DIM + n], acc[mt][nt][r]);
        }
    }
}

extern "C" void kernel_launch(void* const* d_in, const int* in_sizes, int n_in,
                              void* d_out, int out_size, void* d_ws, size_t ws_size,
                              hipStream_t stream) {
    const float* x1 = (const float*)d_in[0];
    const float* x2 = (const float*)d_in[1];
    const float* W  = (const float*)d_in[2];
    const float* b  = (const float*)d_in[3];
    float* out = (float*)d_out;

    const size_t w_bf16_bytes = (size_t)O_DIM * KDIM * sizeof(unsigned short); // 134 MB

    gl_init<<<dim3((L_DIM * O_DIM / 4) / 256), dim3(256), 0, stream>>>(b, out);

    if (ws_size >= w_bf16_bytes) {
        unsigned short* Wb = (unsigned short*)d_ws;
        w_convert<<<dim3(4096), dim3(256), 0, stream>>>(W, Wb);
        // 1D grid: 8(n) x 16(m) x 4(k) = 512 blocks = exact 2/CU at bounds(256,2)
        gl_gemm<<<dim3(8 * 16 * SPLITK), dim3(256), 0, stream>>>(x1, x2, Wb, out);
    } else {
        dim3 grid(O_DIM / BN, L_DIM / BM, 4);
        gl_gemm_fb<<<grid, dim3(256), 0, stream>>>(x1, x2, W, out);
    }
}

// Round 2
// 778.274 us; speedup vs baseline: 19.4354x; 19.4354x over previous
//
#include <hip/hip_runtime.h>
#include <hip/hip_bf16.h>
#include <stdint.h>

// GroupLinear: out[l,o] = sum_{g,i,j} x1[l,g*64+i]*x2[l,g*64+j]*W[o,(g*64+i)*64+j] + b[o]
// Round 9: round-8 schedule (writeB one iter after its loads; raw s_barrier with
// lgkmcnt-only drain so prefetch loads stay in flight across the barrier), but with
// the rule-#20 fix: 2x-unrolled body, two NAMED static reg sets rA/rB_ -- no
// runtime-indexed ext_vector arrays (round 8's rB[it&1] spilled to scratch:
// MfmaUtil 0.74%, 19x VALU inflation, 31x regression).

#define L_DIM 2048
#define H_DIM 1024
#define O_DIM 1024
#define KDIM  65536

constexpr int BM = 128, BN = 128;
constexpr int SPLITK = 4;
constexpr int KITERS = 1024 / SPLITK;   // 256 (g,i) pairs per block, K-advance 64 each
constexpr int BSTR = 72;                // B LDS row stride in shorts (64+8 pad)

typedef __attribute__((ext_vector_type(8))) short bf16x8;
typedef __attribute__((ext_vector_type(8))) unsigned short u16x8;
typedef __attribute__((ext_vector_type(4))) float f32x4;
typedef __attribute__((ext_vector_type(4))) unsigned int u32x4;

__device__ __forceinline__ unsigned short f2b(float x) {
    __hip_bfloat16 h = __float2bfloat16(x);
    unsigned short u;
    __builtin_memcpy(&u, &h, 2);
    return u;
}

__device__ __forceinline__ unsigned pk2(float a, float b) {
    float2 t; t.x = a; t.y = b;
    __hip_bfloat162 h = __float22bfloat162_rn(t);   // v_cvt_pk_bf16_f32
    unsigned u;
    __builtin_memcpy(&u, &h, 4);
    return u;
}

// ---- W fp32 -> bf16: grid-strided, nontemporal fp32 reads, 16B stores ----
__global__ __launch_bounds__(256) void w_convert(const float* __restrict__ W,
                                                 unsigned short* __restrict__ Wb) {
    const size_t nchunk = (size_t)O_DIM * KDIM / 16;          // 16 floats per chunk
    const size_t stride = (size_t)gridDim.x * 256;
    const f32x4* src = reinterpret_cast<const f32x4*>(W);
    u16x8* dst = reinterpret_cast<u16x8*>(Wb);
    for (size_t c = (size_t)blockIdx.x * 256 + threadIdx.x; c < nchunk; c += stride) {
        f32x4 a0 = __builtin_nontemporal_load(src + c * 4 + 0);
        f32x4 a1 = __builtin_nontemporal_load(src + c * 4 + 1);
        f32x4 a2 = __builtin_nontemporal_load(src + c * 4 + 2);
        f32x4 a3 = __builtin_nontemporal_load(src + c * 4 + 3);
        u32x4 p0, p1;
        p0[0] = pk2(a0.x, a0.y); p0[1] = pk2(a0.z, a0.w);
        p0[2] = pk2(a1.x, a1.y); p0[3] = pk2(a1.z, a1.w);
        p1[0] = pk2(a2.x, a2.y); p1[1] = pk2(a2.z, a2.w);
        p1[2] = pk2(a3.x, a3.y); p1[3] = pk2(a3.z, a3.w);
        dst[c * 2 + 0] = __builtin_bit_cast(u16x8, p0);
        dst[c * 2 + 1] = __builtin_bit_cast(u16x8, p1);
    }
}

// ---- out[l][o] = bias[o] (atomic-accumulation base) ----
__global__ __launch_bounds__(256) void gl_init(const float* __restrict__ bias,
                                               float* __restrict__ out) {
    int idx = blockIdx.x * 256 + threadIdx.x;
    int o = (idx * 4) & (O_DIM - 1);
    f32x4 bv = *reinterpret_cast<const f32x4*>(bias + o);
    reinterpret_cast<f32x4*>(out)[idx] = bv;
}

// ---- main GEMM ----
__global__ __launch_bounds__(256, 2) void gl_gemm(const float* __restrict__ x1,
                                                  const float* __restrict__ x2,
                                                  const unsigned short* __restrict__ Wb,
                                                  float* __restrict__ out) {
    __shared__ unsigned short Bb[2][BN * BSTR];   // 2 x 18 KB

    const int tid  = threadIdx.x;
    const int lane = tid & 63;
    const int wid  = tid >> 6;
    const int wm   = (wid >> 1) * 64;
    const int wn   = (wid & 1) * 64;
    const int quad = lane >> 4;
    const int l16  = lane & 15;

    // n in low 3 bits -> all blocks sharing one W n-slab co-locate per XCD (L2 reuse)
    const int id  = blockIdx.x;
    const int n0  = (id & 7) * BN;
    const int m0  = ((id >> 3) & 15) * BM;
    const int kk0 = (id >> 7) * KITERS;     // (g,i)-pair index base, multiple of 64

    unsigned aoff[4];                       // x1/x2 row offsets (floats)
    #pragma unroll
    for (int t = 0; t < 4; ++t)
        aoff[t] = (unsigned)(m0 + wm + t * 16 + l16) * H_DIM;
    const unsigned qo = quad * 8;

    // B staging: thread covers rows (tid>>3)+32p, 16B chunk (tid&7)*8 shorts
    const int brow = tid >> 3;
    const int bcol = (tid & 7) * 8;
    const unsigned short* gB = Wb + (size_t)(n0 + brow) * KDIM + (size_t)kk0 * 64 + bcol;
    const int bl = brow * BSTR + bcol;

    f32x4 acc[4][4] = {};
    f32x4 x2c[4][4];        // per-g x2 slice cache: [mt][ks*2+half]
    u16x8 rA[4], rB_[4];    // NAMED static staging reg sets (rule #20: no runtime idx)
    float xc[4], xn[4];     // x1 current / next

    auto loadB = [&](int t, u16x8 (&r)[4]) {
        const unsigned short* gp = gB + (size_t)t * 64;
        #pragma unroll
        for (int p = 0; p < 4; ++p)
            r[p] = *reinterpret_cast<const u16x8*>(gp + (size_t)p * 32 * KDIM);
    };
    auto loadX1 = [&](int t, float (&v)[4]) {
        const unsigned kc = (unsigned)(kk0 + t);   // x1 col = g*64+i
        #pragma unroll
        for (int mt = 0; mt < 4; ++mt)
            v[mt] = x1[aoff[mt] + kc];
    };
    auto refillX2 = [&](int t) {
        const unsigned gb = (unsigned)(kk0 + t);   // col base = g*64
        #pragma unroll
        for (int mt = 0; mt < 4; ++mt) {
            const float* p = x2 + aoff[mt] + gb + qo;
            x2c[mt][0] = *reinterpret_cast<const f32x4*>(p);
            x2c[mt][1] = *reinterpret_cast<const f32x4*>(p + 4);
            x2c[mt][2] = *reinterpret_cast<const f32x4*>(p + 32);
            x2c[mt][3] = *reinterpret_cast<const f32x4*>(p + 36);
        }
    };

    // BODY(t, bufR, bufW, WSET, LSET):
    //   writeB Bb[bufW] <- WSET (tile t+1, loads issued at sub-iter t-1 -> vmcnt dep old)
    //   loadB tile t+2 -> LSET (stays in flight across the barrier)
    //   compute from Bb[bufR]; raw barrier with lgkmcnt-only drain.
#define GL_BODY(T, BUFR, BUFW, WSET, LSET)                                        \
    {                                                                             \
        const int t_ = (T);                                                       \
        const bool hn1 = (t_ + 1 < KITERS);                                       \
        const bool hn2 = (t_ + 2 < KITERS);                                       \
        if (hn1) {                                                                \
            _Pragma("unroll")                                                     \
            for (int p = 0; p < 4; ++p)                                           \
                *reinterpret_cast<u16x8*>(&Bb[BUFW][bl + p * 32 * BSTR]) = WSET[p];\
        }                                                                         \
        if (hn2) loadB(t_ + 2, LSET);                                             \
        if (hn1) loadX1(t_ + 1, xn);                                              \
        _Pragma("unroll")                                                         \
        for (int ks = 0; ks < 2; ++ks) {                                          \
            const int koff = ks * 32 + qo;                                        \
            bf16x8 af[4], bfr[4];                                                 \
            _Pragma("unroll")                                                     \
            for (int nt = 0; nt < 4; ++nt)                                        \
                bfr[nt] = *reinterpret_cast<const bf16x8*>(                       \
                    &Bb[BUFR][(wn + nt * 16 + l16) * BSTR + koff]);               \
            _Pragma("unroll")                                                     \
            for (int mt = 0; mt < 4; ++mt) {                                      \
                f32x4 lo = x2c[mt][ks * 2]     * xc[mt];                          \
                f32x4 hi = x2c[mt][ks * 2 + 1] * xc[mt];                          \
                u32x4 pk;                                                         \
                pk[0] = pk2(lo.x, lo.y); pk[1] = pk2(lo.z, lo.w);                 \
                pk[2] = pk2(hi.x, hi.y); pk[3] = pk2(hi.z, hi.w);                 \
                af[mt] = __builtin_bit_cast(bf16x8, pk);                          \
            }                                                                     \
            _Pragma("unroll")                                                     \
            for (int mt = 0; mt < 4; ++mt)                                        \
                _Pragma("unroll")                                                 \
                for (int nt = 0; nt < 4; ++nt)                                    \
                    acc[mt][nt] = __builtin_amdgcn_mfma_f32_16x16x32_bf16(        \
                        af[mt], bfr[nt], acc[mt][nt], 0, 0, 0);                   \
        }                                                                         \
        _Pragma("unroll")                                                         \
        for (int mt = 0; mt < 4; ++mt) xc[mt] = xn[mt];                           \
        __builtin_amdgcn_sched_barrier(0);                                        \
        asm volatile("s_waitcnt lgkmcnt(0)" ::: "memory");                        \
        __builtin_amdgcn_s_barrier();                                             \
        __builtin_amdgcn_sched_barrier(0);                                        \
    }

    // prologue: stage tile 0 (one-time vmcnt-latency stall), prefetch tile 1 regs
    loadB(0, rA);
    loadX1(0, xc);
    #pragma unroll
    for (int p = 0; p < 4; ++p)
        *reinterpret_cast<u16x8*>(&Bb[0][bl + p * 32 * BSTR]) = rA[p];
    loadB(1, rB_);
    __builtin_amdgcn_sched_barrier(0);
    asm volatile("s_waitcnt lgkmcnt(0)" ::: "memory");
    __builtin_amdgcn_s_barrier();
    __builtin_amdgcn_sched_barrier(0);

    for (int itb = 0; itb < KITERS; itb += 2) {
        if ((itb & 63) == 0) refillX2(itb);      // g-boundary only hits even sub-iters
        // even sub-iter t=itb:   read Bb[0], write tile t+1 (rB_) -> Bb[1], load t+2 -> rA
        GL_BODY(itb,     0, 1, rB_, rA)
        // odd  sub-iter t=itb+1: read Bb[1], write tile t+2 (rA) -> Bb[0], load t+3 -> rB_
        GL_BODY(itb + 1, 1, 0, rA, rB_)
    }
#undef GL_BODY

    // Epilogue: split-K partials. C/D: row(m)=quad*4+reg, col(n)=lane&15.
    #pragma unroll
    for (int mt = 0; mt < 4; ++mt) {
        const int mb = m0 + wm + mt * 16 + quad * 4;
        #pragma unroll
        for (int nt = 0; nt < 4; ++nt) {
            const int n = n0 + wn + nt * 16 + l16;
            #pragma unroll
            for (int r = 0; r < 4; ++r)
                unsafeAtomicAdd(&out[(mb + r) * O_DIM + n], acc[mt][nt][r]);
        }
    }
}

// ---- fallback (fp32 W, LDS staging) if workspace too small for bf16 W ----
constexpr int STR = 72;
__global__ __launch_bounds__(256, 2) void gl_gemm_fb(const float* __restrict__ x1,
                                                     const float* __restrict__ x2,
                                                     const float* __restrict__ W,
                                                     float* __restrict__ out) {
    __shared__ unsigned short Ab[BM * STR];
    __shared__ unsigned short Bb2[BM * STR];

    const int tid  = threadIdx.x;
    const int lane = tid & 63;
    const int wid  = tid >> 6;
    const int wm   = (wid >> 1) * 64;
    const int wn   = (wid & 1) * 64;
    const int quad = lane >> 4;
    const int l16  = lane & 15;
    const int m0   = blockIdx.y * BM;
    const int n0   = blockIdx.x * BN;
    const int kk0  = blockIdx.z * (1024 / 4);

    const int srow = tid >> 4;
    const int scol = (tid & 15) * 4;

    f32x4 acc[4][4] = {};

    for (int kk = kk0; kk < kk0 + (1024 / 4); ++kk) {
        const int g = kk >> 6;
        const int i = kk & 63;
        __syncthreads();
        #pragma unroll
        for (int c = 0; c < 8; ++c) {
            const int r = srow + c * 16;
            const float x1v = x1[(m0 + r) * H_DIM + g * 64 + i];
            const f32x4 v = *reinterpret_cast<const f32x4*>(
                &x2[(m0 + r) * H_DIM + g * 64 + scol]);
            ushort4 h;
            h.x = f2b(v.x * x1v); h.y = f2b(v.y * x1v);
            h.z = f2b(v.z * x1v); h.w = f2b(v.w * x1v);
            *reinterpret_cast<ushort4*>(&Ab[r * STR + scol]) = h;
        }
        #pragma unroll
        for (int c = 0; c < 8; ++c) {
            const int r = srow + c * 16;
            const f32x4 v = *reinterpret_cast<const f32x4*>(
                &W[(size_t)(n0 + r) * KDIM + (size_t)kk * 64 + scol]);
            ushort4 h;
            h.x = f2b(v.x); h.y = f2b(v.y); h.z = f2b(v.z); h.w = f2b(v.w);
            *reinterpret_cast<ushort4*>(&Bb2[r * STR + scol]) = h;
        }
        __syncthreads();
        #pragma unroll
        for (int ks = 0; ks < 2; ++ks) {
            const int koff = ks * 32 + quad * 8;
            bf16x8 af[4], bfr[4];
            #pragma unroll
            for (int mt = 0; mt < 4; ++mt)
                af[mt] = *reinterpret_cast<const bf16x8*>(
                    &Ab[(wm + mt * 16 + l16) * STR + koff]);
            #pragma unroll
            for (int nt = 0; nt < 4; ++nt)
                bfr[nt] = *reinterpret_cast<const bf16x8*>(
                    &Bb2[(wn + nt * 16 + l16) * STR + koff]);
            #pragma unroll
            for (int mt = 0; mt < 4; ++mt)
                #pragma unroll
                for (int nt = 0; nt < 4; ++nt)
                    acc[mt][nt] = __builtin_amdgcn_mfma_f32_16x16x32_bf16(
                        af[mt], bfr[nt], acc[mt][nt], 0, 0, 0);
        }
    }
    #pragma unroll
    for (int mt = 0; mt < 4; ++mt) {
        const int mb = m0 + wm + mt * 16 + quad * 4;
        #pragma unroll
        for (int nt = 0; nt < 4; ++nt) {
            const int n = n0 + wn + nt * 16 + l16;
            #pragma unroll
            for (int r = 0; r < 4; ++r)
                unsafeAtomicAdd(&out[(mb + r) * O_DIM + n], acc[mt][nt][r]);
        }
    }
}

extern "C" void kernel_launch(void* const* d_in, const int* in_sizes, int n_in,
                              void* d_out, int out_size, void* d_ws, size_t ws_size,
                              hipStream_t stream) {
    const float* x1 = (const float*)d_in[0];
    const float* x2 = (const float*)d_in[1];
    const float* W  = (const float*)d_in[2];
    const float* b  = (const float*)d_in[3];
    float* out = (float*)d_out;

    const size_t w_bf16_bytes = (size_t)O_DIM * KDIM * sizeof(unsigned short); // 134 MB

    gl_init<<<dim3((L_DIM * O_DIM / 4) / 256), dim3(256), 0, stream>>>(b, out);

    if (ws_size >= w_bf16_bytes) {
        unsigned short* Wb = (unsigned short*)d_ws;
        w_convert<<<dim3(4096), dim3(256), 0, stream>>>(W, Wb);
        // 1D grid: 8(n) x 16(m) x 4(k) = 512 blocks = exact 2/CU at bounds(256,2)
        gl_gemm<<<dim3(8 * 16 * SPLITK), dim3(256), 0, stream>>>(x1, x2, Wb, out);
    } else {
        dim3 grid(O_DIM / BN, L_DIM / BM, 4);
        gl_gemm_fb<<<grid, dim3(256), 0, stream>>>(x1, x2, W, out);
    }
}